// Round 5
// baseline (555.187 us; speedup 1.0000x reference)
//
#include <hip/hip_runtime.h>

#define BB   2
#define TT   512
#define NF   6
#define DD   32
#define HIDD 128
#define NHH  4
#define HDD  32
#define GHH  32
#define FDD  128
#define LL   (TT*NF)      // 3072
#define EPSF 1e-5f
#define NQT32 96          // 32-row q-tiles per (b,h)

// ---------------------------------------------------------------------------
// Kernel 1: gater + gated QKV, 4 tokens per 64-thread block (1536 blocks).
// Q/K/V written HEAD-MAJOR: [b, h, L, 32] for contiguous attn tile loads.
// ---------------------------------------------------------------------------
__global__ __launch_bounds__(64) void gate_qkv_kernel(
    const float* __restrict__ x,
    const float* __restrict__ g_ln_w, const float* __restrict__ g_ln_b,
    const float* __restrict__ g_w1,   const float* __restrict__ g_b1,
    const float* __restrict__ g_w2,   const float* __restrict__ g_b2,
    const float* __restrict__ q_w,    const float* __restrict__ q_b,
    const float* __restrict__ k_w,    const float* __restrict__ k_b,
    const float* __restrict__ v_w,    const float* __restrict__ v_b,
    float* __restrict__ Q, float* __restrict__ K, float* __restrict__ V)
{
    const int tok0 = blockIdx.x * 4;
    const int lane = threadIdx.x;

    __shared__ float xs[4][DD];
    __shared__ float lns[4][DD];
    __shared__ float hs[4][GHH];
    __shared__ float gate_s[4];

    #pragma unroll
    for (int i = 0; i < 2; i++) {
        int idx = lane + i * 64;
        xs[idx >> 5][idx & 31] = x[(size_t)tok0 * DD + idx];
    }
    __syncthreads();

    const int tk = lane >> 5;
    const int d5 = lane & 31;

    #pragma unroll
    for (int tt = 0; tt < 2; tt++) {
        int t = tt * 2 + tk;
        float xv = xs[t][d5];
        float s1 = xv, s2 = xv * xv;
        #pragma unroll
        for (int m = 16; m >= 1; m >>= 1) {
            s1 += __shfl_xor(s1, m, 32);
            s2 += __shfl_xor(s2, m, 32);
        }
        float mu  = s1 * (1.0f / DD);
        float var = s2 * (1.0f / DD) - mu * mu;
        float r   = rsqrtf(var + EPSF);
        lns[t][d5] = (xv - mu) * r * g_ln_w[d5] + g_ln_b[d5];
    }
    __syncthreads();

    #pragma unroll
    for (int tt = 0; tt < 2; tt++) {
        int t = tt * 2 + tk;
        float acc = g_b1[d5];
        #pragma unroll
        for (int d = 0; d < DD; d++) acc += lns[t][d] * g_w1[d * GHH + d5];
        hs[t][d5] = acc / (1.0f + __expf(-acc));
    }
    __syncthreads();

    #pragma unroll
    for (int tt = 0; tt < 2; tt++) {
        int t = tt * 2 + tk;
        float p = hs[t][d5] * g_w2[d5];
        #pragma unroll
        for (int m = 16; m >= 1; m >>= 1) p += __shfl_xor(p, m, 32);
        if (d5 == 0) gate_s[t] = 1.0f / (1.0f + __expf(-(p + g_b2[0])));
    }
    __syncthreads();

    float aq0[4], aq1[4], ak0[4], ak1[4], av0[4], av1[4];
    #pragma unroll
    for (int t = 0; t < 4; t++) {
        aq0[t] = q_b[lane]; aq1[t] = q_b[lane + 64];
        ak0[t] = k_b[lane]; ak1[t] = k_b[lane + 64];
        av0[t] = v_b[lane]; av1[t] = v_b[lane + 64];
    }
    #pragma unroll
    for (int d = 0; d < DD; d++) {
        float wq0 = q_w[d * HIDD + lane], wq1 = q_w[d * HIDD + lane + 64];
        float wk0 = k_w[d * HIDD + lane], wk1 = k_w[d * HIDD + lane + 64];
        float wv0 = v_w[d * HIDD + lane], wv1 = v_w[d * HIDD + lane + 64];
        #pragma unroll
        for (int t = 0; t < 4; t++) {
            float xd = xs[t][d];
            aq0[t] += xd * wq0; aq1[t] += xd * wq1;
            ak0[t] += xd * wk0; ak1[t] += xd * wk1;
            av0[t] += xd * wv0; av1[t] += xd * wv1;
        }
    }

    const int b  = tok0 / LL;
    const int l0 = tok0 - b * LL;
    const int hA = lane >> 5;
    #pragma unroll
    for (int t = 0; t < 4; t++) {
        float g = gate_s[t];
        size_t p0 = ((size_t)(b * NHH + hA)     * LL + l0 + t) * HDD + d5;
        size_t p1 = ((size_t)(b * NHH + 2 + hA) * LL + l0 + t) * HDD + d5;
        Q[p0] = aq0[t] * g;  Q[p1] = aq1[t] * g;
        K[p0] = ak0[t] * g;  K[p1] = ak1[t] * g;
        V[p0] = av0[t] * g;  V[p1] = av1[t] * g;
    }
}

// ---------------------------------------------------------------------------
// Kernel 2a: split-K flash attention partials.
// Grid (96 qtiles, NCH chunks, 8 bh); block = 64 threads = 1 wave.
// Thread = (rowgrp g: 4 rows, key-parity kp, dim-slice sl: 8 dims).
// Each K/V LDS read is reused across 4 rows -> 64 B/pair register traffic.
// Partial (o, m, l) per (bh, qt, chunk, row) -> P workspace.
// ---------------------------------------------------------------------------
__global__ __launch_bounds__(64) void attn_partial(
    const float* __restrict__ Q, const float* __restrict__ K,
    const float* __restrict__ V, float* __restrict__ P,
    int C, int NCH)
{
    const int qt  = blockIdx.x;            // 0..95
    const int ch  = blockIdx.y;            // 0..NCH-1
    const int bh  = blockIdx.z;            // 0..7
    const int j0c = C * ch;
    const int jmax_blk = ((qt * 32 + 31) / NF + 1) * NF;
    if (j0c >= jmax_blk) return;           // dead chunk for every row

    const int tid = threadIdx.x;
    const int g   = tid >> 3;              // 0..7
    const int kp  = (tid >> 2) & 1;        // 0..1
    const int sl  = tid & 3;               // 0..3 (dims sl*8..sl*8+7)

    const size_t hb  = (size_t)bh * LL;
    const int    ig0 = qt * 32 + g * 4;

    // stride 36 floats: 16B-aligned rows; per wave-instr the 8 distinct
    // (kp,sl) addresses start at banks 4j+2kp... pattern covers all 32
    // banks once -> conflict-free, 8-way (g) broadcast.
    __shared__ __align__(16) float Kt[32][36];
    __shared__ __align__(16) float Vt[32][36];

    const float scale = 0.17677669529663688f;  // 1/sqrt(32)
    float q[4][8], o[4][8];
    float m[4], l[4];
    int   jend[4];
    #pragma unroll
    for (int r = 0; r < 4; r++) {
        const int ig = ig0 + r;
        const float4* qp = (const float4*)(Q + (hb + ig) * HDD + sl * 8);
        float4 a = qp[0], b = qp[1];
        q[r][0]=a.x*scale; q[r][1]=a.y*scale; q[r][2]=a.z*scale; q[r][3]=a.w*scale;
        q[r][4]=b.x*scale; q[r][5]=b.y*scale; q[r][6]=b.z*scale; q[r][7]=b.w*scale;
        #pragma unroll
        for (int d = 0; d < 8; d++) o[r][d] = 0.0f;
        m[r] = -1e30f; l[r] = 0.0f;
        jend[r] = (ig / NF + 1) * NF - j0c;   // may be <= 0 (dead row)
    }

    const int nk    = min(jmax_blk - j0c, C);
    const int ntile = (nk + 31) >> 5;

    for (int kt = 0; kt < ntile; kt++) {
        const int j0 = j0c + kt * 32;
        __syncthreads();
        #pragma unroll
        for (int i = 0; i < 4; i++) {
            int slot = tid + i * 64;           // 0..255 float4 slots
            int jr = slot >> 3, c4 = slot & 7;
            const float4 kv = *((const float4*)(K + (hb + j0 + jr) * HDD) + c4);
            const float4 vv = *((const float4*)(V + (hb + j0 + jr) * HDD) + c4);
            *((float4*)(&Kt[jr][0]) + c4) = kv;
            *((float4*)(&Vt[jr][0]) + c4) = vv;
        }
        __syncthreads();

        const int jb = kt * 32;
        #pragma unroll
        for (int bb = 0; bb < 2; bb++) {
            float p[4][8];
            // scores: 8 keys x 4 rows, 8-dim partial dots
            #pragma unroll
            for (int u = 0; u < 8; u++) {
                const int jl = bb * 16 + u * 2 + kp;
                const float4 k0 = *(const float4*)(&Kt[jl][sl * 8]);
                const float4 k1 = *(const float4*)(&Kt[jl][sl * 8 + 4]);
                #pragma unroll
                for (int r = 0; r < 4; r++) {
                    p[r][u] = q[r][0]*k0.x + q[r][1]*k0.y + q[r][2]*k0.z + q[r][3]*k0.w
                            + q[r][4]*k1.x + q[r][5]*k1.y + q[r][6]*k1.z + q[r][7]*k1.w;
                }
            }
            // reduce partial dots across the 4 sl lanes (butterfly)
            #pragma unroll
            for (int r = 0; r < 4; r++)
                #pragma unroll
                for (int u = 0; u < 8; u++) {
                    float t = p[r][u];
                    t += __shfl_xor(t, 1);
                    t += __shfl_xor(t, 2);
                    p[r][u] = t;
                }
            // online softmax per row; overwrite p with exp weights
            #pragma unroll
            for (int r = 0; r < 4; r++) {
                const int je = jend[r] - jb;
                float mx = m[r];
                #pragma unroll
                for (int u = 0; u < 8; u++) {
                    const int jl = bb * 16 + u * 2 + kp;
                    float s = (jl < je) ? p[r][u] : -1e30f;
                    p[r][u] = s;
                    mx = fmaxf(mx, s);
                }
                const float corr = __expf(m[r] - mx);
                m[r] = mx;
                float ls = 0.0f;
                #pragma unroll
                for (int u = 0; u < 8; u++) {
                    const int jl = bb * 16 + u * 2 + kp;
                    float e = __expf(p[r][u] - mx);
                    e = (jl < je) ? e : 0.0f;    // kills exp(0)=1 for dead rows
                    p[r][u] = e;
                    ls += e;
                }
                l[r] = l[r] * corr + ls;
                #pragma unroll
                for (int d = 0; d < 8; d++) o[r][d] *= corr;
            }
            // V accumulation: each Vt read serves 4 rows
            #pragma unroll
            for (int u = 0; u < 8; u++) {
                const int jl = bb * 16 + u * 2 + kp;
                const float4 v0 = *(const float4*)(&Vt[jl][sl * 8]);
                const float4 v1 = *(const float4*)(&Vt[jl][sl * 8 + 4]);
                #pragma unroll
                for (int r = 0; r < 4; r++) {
                    const float e = p[r][u];
                    o[r][0] += e*v0.x; o[r][1] += e*v0.y; o[r][2] += e*v0.z; o[r][3] += e*v0.w;
                    o[r][4] += e*v1.x; o[r][5] += e*v1.y; o[r][6] += e*v1.z; o[r][7] += e*v1.w;
                }
            }
        }
    }

    // merge the two key-parity partitions (lanes xor 4)
    #pragma unroll
    for (int r = 0; r < 4; r++) {
        float mo = __shfl_xor(m[r], 4);
        float mm = fmaxf(m[r], mo);
        float a  = __expf(m[r] - mm);
        float lw = l[r] * a;
        lw += __shfl_xor(lw, 4);
        #pragma unroll
        for (int d = 0; d < 8; d++) {
            float ow = o[r][d] * a;
            ow += __shfl_xor(ow, 4);
            o[r][d] = ow;
        }
        m[r] = mm; l[r] = lw;
    }

    if (kp == 0) {
        const size_t base = (((size_t)bh * NQT32 + qt) * NCH + ch) * 32;
        #pragma unroll
        for (int r = 0; r < 4; r++) {
            float* pr = P + (base + g * 4 + r) * 36;
            float4 w0, w1;
            w0.x=o[r][0]; w0.y=o[r][1]; w0.z=o[r][2]; w0.w=o[r][3];
            w1.x=o[r][4]; w1.y=o[r][5]; w1.z=o[r][6]; w1.w=o[r][7];
            *((float4*)(pr + sl * 8))     = w0;
            *((float4*)(pr + sl * 8 + 4)) = w1;
            if (sl == 0) { pr[32] = m[r]; pr[33] = l[r]; }
        }
    }
}

// ---------------------------------------------------------------------------
// Kernel 2b: combine split-K partials (flash-decoding merge), write [b,L,128].
// Grid (48, 4, 2); block 256 = 64 rows x 4 dim-lanes.
// ---------------------------------------------------------------------------
__global__ __launch_bounds__(256) void attn_combine(
    const float* __restrict__ P, float* __restrict__ A, int C, int NCH)
{
    const int rb = blockIdx.x;
    const int h  = blockIdx.y;
    const int b  = blockIdx.z;
    const int tid = threadIdx.x;
    const int rl = tid >> 2;
    const int ln = tid & 3;
    const int ig = rb * 64 + rl;
    const int bh = b * NHH + h;
    const int jmax = (ig / NF + 1) * NF;
    const int nch = min(NCH, (jmax + C - 1) / C);
    const int qt = ig >> 5;
    const int r  = ig & 31;

    float M = -1e30f, L = 0.0f, O[8];
    #pragma unroll
    for (int d = 0; d < 8; d++) O[d] = 0.0f;

    for (int c = 0; c < nch; c++) {
        const float* pr = P + ((((size_t)bh * NQT32 + qt) * NCH + c) * 32 + r) * 36;
        const float mc = pr[32], lc = pr[33];
        const float4 o0 = *((const float4*)(pr + ln * 8));
        const float4 o1 = *((const float4*)(pr + ln * 8 + 4));
        const float mm = fmaxf(M, mc);
        const float sa = __expf(M - mm), sb = __expf(mc - mm);
        M = mm;
        L = L * sa + lc * sb;
        O[0] = O[0]*sa + o0.x*sb; O[1] = O[1]*sa + o0.y*sb;
        O[2] = O[2]*sa + o0.z*sb; O[3] = O[3]*sa + o0.w*sb;
        O[4] = O[4]*sa + o1.x*sb; O[5] = O[5]*sa + o1.y*sb;
        O[6] = O[6]*sa + o1.z*sb; O[7] = O[7]*sa + o1.w*sb;
    }
    const float inv = 1.0f / L;
    float4 w0, w1;
    w0.x=O[0]*inv; w0.y=O[1]*inv; w0.z=O[2]*inv; w0.w=O[3]*inv;
    w1.x=O[4]*inv; w1.y=O[5]*inv; w1.z=O[6]*inv; w1.w=O[7]*inv;
    float* dst = A + ((size_t)(b * LL + ig)) * HIDD + h * HDD + ln * 8;
    *((float4*)dst)       = w0;
    *((float4*)(dst + 4)) = w1;
}

// ---------------------------------------------------------------------------
// Kernel 3: mean-pool -> o-proj -> LN -> f-proj -> SiLU. Block per (t, b).
// ---------------------------------------------------------------------------
__global__ __launch_bounds__(128) void final_kernel(
    const float* __restrict__ A,
    const float* __restrict__ o_w,    const float* __restrict__ o_b,
    const float* __restrict__ f_ln_w, const float* __restrict__ f_ln_b,
    const float* __restrict__ f_w,    const float* __restrict__ f_b,
    float* __restrict__ out)
{
    const int t = blockIdx.x;
    const int b = blockIdx.y;
    const int d = threadIdx.x;

    __shared__ float ms[HIDD];
    __shared__ float lnbuf[HIDD];
    __shared__ float w1[2], w2[2];

    float acc = 0.0f;
    #pragma unroll
    for (int f = 0; f < NF; f++)
        acc += A[((size_t)(b * LL + t * NF + f)) * HIDD + d];
    acc *= (1.0f / NF);
    ms[d] = acc;
    __syncthreads();

    float ov = o_b[d];
    for (int k = 0; k < HIDD; k++) ov += ms[k] * o_w[k * HIDD + d];

    float s1 = ov, s2 = ov * ov;
    #pragma unroll
    for (int m = 32; m >= 1; m >>= 1) { s1 += __shfl_xor(s1, m); s2 += __shfl_xor(s2, m); }
    if ((d & 63) == 0) { w1[d >> 6] = s1; w2[d >> 6] = s2; }
    __syncthreads();
    float S1 = w1[0] + w1[1], S2 = w2[0] + w2[1];
    float mu  = S1 * (1.0f / HIDD);
    float var = S2 * (1.0f / HIDD) - mu * mu;
    float r   = rsqrtf(var + EPSF);
    float lnv = (ov - mu) * r * f_ln_w[d] + f_ln_b[d];
    lnbuf[d] = lnv;
    __syncthreads();

    float fv = f_b[d];
    for (int k = 0; k < HIDD; k++) fv += lnbuf[k] * f_w[k * HIDD + d];
    fv = fv / (1.0f + __expf(-fv));

    out[((size_t)(b * TT + t)) * FDD + d] = fv;
}

// ---------------------------------------------------------------------------
extern "C" void kernel_launch(void* const* d_in, const int* in_sizes, int n_in,
                              void* d_out, int out_size, void* d_ws, size_t ws_size,
                              hipStream_t stream)
{
    const float* x      = (const float*)d_in[0];
    const float* g_ln_w = (const float*)d_in[1];
    const float* g_ln_b = (const float*)d_in[2];
    const float* g_w1   = (const float*)d_in[3];
    const float* g_b1   = (const float*)d_in[4];
    const float* g_w2   = (const float*)d_in[5];
    const float* g_b2   = (const float*)d_in[6];
    const float* q_w    = (const float*)d_in[7];
    const float* q_b    = (const float*)d_in[8];
    const float* k_w    = (const float*)d_in[9];
    const float* k_b    = (const float*)d_in[10];
    const float* v_w    = (const float*)d_in[11];
    const float* v_b    = (const float*)d_in[12];
    const float* o_w    = (const float*)d_in[13];
    const float* o_b    = (const float*)d_in[14];
    const float* f_ln_w = (const float*)d_in[15];
    const float* f_ln_b = (const float*)d_in[16];
    const float* f_w    = (const float*)d_in[17];
    const float* f_b    = (const float*)d_in[18];

    const size_t stride = (size_t)BB * NHH * LL * HDD;   // 786432 floats
    float* Qw = (float*)d_ws;
    float* Kw = Qw + stride;
    float* Vw = Kw + stride;
    float* Aw = Vw + stride;                             // [B, L, HID]
    float* Pw = Aw + stride;                             // split-K partials

    // choose chunk count from available scratch (deterministic per ws_size)
    const long long unit = 8LL * NQT32 * 32 * 36;        // floats per chunk level
    long long avail = (long long)(ws_size / 4) - 4LL * (long long)stride;
    int NCH = (int)(avail / unit);
    if (NCH > 7) NCH = 7;
    if (NCH < 1) NCH = 1;
    const int C = 32 * ((96 + NCH - 1) / NCH);           // keys per chunk (mult of 32)

    gate_qkv_kernel<<<(BB * LL) / 4, 64, 0, stream>>>(
        x, g_ln_w, g_ln_b, g_w1, g_b1, g_w2, g_b2,
        q_w, q_b, k_w, k_b, v_w, v_b, Qw, Kw, Vw);

    attn_partial<<<dim3(NQT32, NCH, BB * NHH), 64, 0, stream>>>(
        Qw, Kw, Vw, Pw, C, NCH);

    attn_combine<<<dim3(LL / 64, NHH, BB), 256, 0, stream>>>(Pw, Aw, C, NCH);

    final_kernel<<<dim3(TT, BB), 128, 0, stream>>>(
        Aw, o_w, o_b, f_ln_w, f_ln_b, f_w, f_b, (float*)d_out);
}